// Round 10
// baseline (4783.500 us; speedup 1.0000x reference)
//
#include <hip/hip_runtime.h>
#include <hip/hip_bf16.h>
#include <math.h>

#define B_ 256
#define L_ 512
#define V_ 256
#define E_ 256
#define H_ 1024

typedef float  f32x4  __attribute__((ext_vector_type(4)));
typedef short  bf16x8 __attribute__((ext_vector_type(8)));
typedef unsigned int u32;
typedef unsigned char u8;

static __device__ __forceinline__ ushort f2bf(float v) {
    __hip_bfloat16 b = __float2bfloat16(v);
    return *reinterpret_cast<ushort*>(&b);
}

// fast tanh: 1 - 2/(exp(2z)+1); exact limits, ~1e-7 rel err
static __device__ __forceinline__ float ftanh(float z) {
    float e = __expf(2.f * z);
    return 1.f - 2.f / (e + 1.f);
}

// ---------- prep kernels (unchanged, R9-proven) ----------
__global__ void k_transpose_bf16(const float* __restrict__ in, ushort* __restrict__ out,
                                 int R, int C) {
    __shared__ float tile[64][65];
    int bx = blockIdx.x, by = blockIdx.y;
    int tid = threadIdx.x;
    int g = tid >> 6, l = tid & 63;
    for (int i = 0; i < 16; ++i) {
        int r = g * 16 + i;
        tile[r][l] = in[(size_t)(by * 64 + r) * C + bx * 64 + l];
    }
    __syncthreads();
    for (int i = 0; i < 16; ++i) {
        int c = g * 16 + i;
        out[(size_t)(bx * 64 + c) * R + by * 64 + l] = f2bf(tile[l][c]);
    }
}

__global__ void k_zero(u32* __restrict__ p, int n) {
    int i = blockIdx.x * blockDim.x + threadIdx.x;
    if (i < n) p[i] = 0u;
}

__global__ void k_pack_h0(const float* __restrict__ hid, ushort* __restrict__ ringA,
                          ushort* __restrict__ ringB) {
    int i = blockIdx.x * blockDim.x + threadIdx.x;
    ushort v = f2bf(hid[i]);
    int half = i >> 17;
    int off = i & 131071;
    if (half == 0) ringA[off] = v; else ringB[off] = v;
}

__global__ void k_proj(const float* __restrict__ emb, const float* __restrict__ We,
                       float* __restrict__ proj) {
    __shared__ float er[E_];
    int t = blockIdx.x;
    int h = blockIdx.y * 256 + threadIdx.x;
    er[threadIdx.x] = emb[t * E_ + threadIdx.x];
    __syncthreads();
    float acc = 0.f;
#pragma unroll 8
    for (int e = 0; e < E_; ++e) acc += er[e] * We[(size_t)e * H_ + h];
    proj[(size_t)t * H_ + h] = acc;
}

// ---------- persistent scan: wave-role pipeline, ONE barrier per phase ----------
// Block (rg=bid&7, cg=bid>>3): 16x32 tile in each half. Per phase p (hx=p&1,
// s=p>>1; px=(p-1)&1, ps=(p-1)>>1):
//   w0,w1 (A): MFMA H^px_{ps+1} from panel[px] -> tanh -> per-wave stile ->
//              coalesced 16B H-stores -> vmcnt(0) -> per-wave flag; w0 then
//              end-polls flags needed by phase p+1.
//   w2,w3 (B): issue 16 stage loads for H^hx_s (fly under compute); w3 stores
//              pending logits (red parity p^1); both MFMA logits col ps-1 ->
//              red[p&1]; vmcnt(0); ds_write panel[hx].
// Transport: sc0 sc1 stores/loads at L3 coherence point, drain-then-flag,
// per-(block,wave) flags, blockIdx-only mapping (no placement assumptions).
__global__ __launch_bounds__(256, 1) void k_scan(
    const int* __restrict__ xs, const float* __restrict__ proj,
    const ushort* __restrict__ WhT, const ushort* __restrict__ WoT,
    ushort* __restrict__ ringA, ushort* __restrict__ ringB,
    float* __restrict__ logits, float* __restrict__ final_h,
    u8* __restrict__ flags)
{
    __shared__ ushort lds_w[32 * 1024];     // W_h^T cols [c0,+32), swizzled (64KB)
    __shared__ ushort panel[2][16 * 1024];  // H panels, swizzled (2x32KB)
    __shared__ float  red[2][2][16][17];    // logits partials, parity x khalf (8.7KB)
    __shared__ ushort stile[2][16][16];     // per-A-wave H tile (1KB)

    int tid = threadIdx.x;
    int w = tid >> 6, lane = tid & 63;
    int l15 = lane & 15, l4 = lane >> 4;
    int bid = blockIdx.x;
    int rg = bid & 7, cg = bid >> 3;
    int c0 = cg * 32;
    int as = (l15 & 7) << 4;

    // --- preload W slice once; drain before loop
    {
        const char* wsrc = (const char*)(WhT + (size_t)c0 * H_);
        char* wd = (char*)lds_w;
        for (int i = 0; i < 16; ++i) {
            int chunk = (w * 16 + i) * 1024;
            int o = chunk + lane * 16;
            int row = o >> 11, b = o & 2047;
            int so = row * 2048 + (b ^ ((row & 7) << 4));
            __builtin_amdgcn_global_load_lds(
                (const __attribute__((address_space(1))) void*)(wsrc + so),
                (__attribute__((address_space(3))) void*)(wd + chunk), 16, 0, 0);
        }
    }
    asm volatile("s_waitcnt vmcnt(0)" ::: "memory");
    __syncthreads();

    // A-wave constants (w<2): B-frag from lds_w rows (w*16+l15); (16 = 0 mod 8 -> swizzle 'as')
    const char* wa = (const char*)lds_w + (size_t)((w & 1) * 16 + l15) * 2048;
    // B-wave constants: vocab tile (cg<16), K half per wave
    int vcol0 = (cg & 15) * 16;
    const ushort* wo = WoT + (size_t)(vcol0 + l15) * H_;
    int sl = tid - 128;                       // stage lane 0..127 (w2,w3)

    for (int p = 0; p <= 2 * L_ + 3; ++p) {
        int hx = p & 1, s = p >> 1;
        int px = (p - 1) & 1, ps = (p - 1) >> 1;
        int qx = (p - 2) & 1, qs = (p - 2) >> 1;      // pending logits meta
        bool doStage = (p <= 2 * L_ + 1);
        bool doA = (p >= 1) && (ps < L_);
        bool doB = (p >= 1) && (ps >= 1) && (ps <= L_) && (cg < 16);
        bool doPend = (p >= 2) && (qs >= 1) && (qs <= L_) && (cg < 16);

        if (w < 2) {
            // ================= A waves =================
            if (doA) {
                // pv gather first (latency hides under MFMA)
                float pv[4];
#pragma unroll
                for (int j = 0; j < 4; ++j) {
                    int grow = px * 128 + rg * 16 + l4 * 4 + j;
                    pv[j] = proj[(size_t)xs[grow * L_ + ps] * H_ + c0 + w * 16 + l15];
                }
                const char* ha = (const char*)panel[px] + l15 * 2048;
                f32x4 acc0 = {0.f,0.f,0.f,0.f}, acc1 = {0.f,0.f,0.f,0.f};
#pragma unroll
                for (int kk = 0; kk < 32; kk += 2) {
                    int kb0 = (kk * 32 + l4 * 8) * 2;
                    int kb1 = ((kk + 1) * 32 + l4 * 8) * 2;
                    bf16x8 af0 = *(const bf16x8*)(ha + (kb0 ^ as));
                    bf16x8 bf0 = *(const bf16x8*)(wa + (kb0 ^ as));
                    bf16x8 af1 = *(const bf16x8*)(ha + (kb1 ^ as));
                    bf16x8 bf1 = *(const bf16x8*)(wa + (kb1 ^ as));
                    acc0 = __builtin_amdgcn_mfma_f32_16x16x32_bf16(af0, bf0, acc0, 0, 0, 0);
                    acc1 = __builtin_amdgcn_mfma_f32_16x16x32_bf16(af1, bf1, acc1, 0, 0, 0);
                }
#pragma unroll
                for (int j = 0; j < 4; ++j) {
                    int lrow = l4 * 4 + j;
                    float hv = ftanh((acc0[j] + acc1[j]) + pv[j]);
                    stile[w][lrow][l15] = f2bf(hv);
                    if (ps == L_ - 1) {
                        int grow = px * 128 + rg * 16 + lrow;
                        final_h[(size_t)grow * H_ + c0 + w * 16 + l15] = hv;
                    }
                }
                asm volatile("s_waitcnt lgkmcnt(0)" ::: "memory");   // stile visible wave-wide
                ushort* ringW = px ? ringB : ringA;
                if (lane < 32) {
                    int row = lane >> 1, half = lane & 1;
                    f32x4 d = *(const f32x4*)&stile[w][row][half * 8];
                    char* dst = (char*)(ringW + (size_t)((ps + 1) & 1) * 128 * H_
                                        + (size_t)(rg * 16 + row) * H_ + c0 + w * 16 + half * 8);
                    asm volatile("global_store_dwordx4 %0, %1, off sc0 sc1"
                                 :: "v"(dst), "v"(d) : "memory");
                }
                asm volatile("s_waitcnt vmcnt(0)" ::: "memory");     // data at L3
                if (lane == 0) {
                    u8* fdst = flags + ((size_t)(px * 8 + rg) * 513 + (ps + 1)) * 64 + cg * 2 + w;
                    u32 one = 1u;
                    asm volatile("global_store_byte %0, %1, off sc0 sc1"
                                 :: "v"(fdst), "v"(one) : "memory");
                }
            }
            // end-poll (w0): confirm flags for phase p+1's stage
            if (w == 0) {
                int pn = p + 1;
                if (pn <= 2 * L_ + 1 && (pn >> 1) >= 1) {
                    int hxn = pn & 1, sn = pn >> 1;
                    const u8* fp = flags + ((size_t)(hxn * 8 + rg) * 513 + sn) * 64 + lane;
                    u32 v;
                    while (true) {
                        asm volatile("global_load_ubyte %0, %1, off sc0 sc1\n\t"
                                     "s_waitcnt vmcnt(0)" : "=v"(v) : "v"(fp) : "memory");
                        if (__ballot(v != 0u) == ~0ull) break;
                    }
                }
            }
        } else {
            // ================= B waves =================
            // 1. issue stage loads for H^hx_s (poll was confirmed last phase)
            f32x4 tv[16];
            if (doStage) {
                const ushort* ringR = hx ? ringB : ringA;
                const char* hsrc = (const char*)(ringR + (size_t)(s & 1) * 128 * H_
                                                 + (size_t)(rg * 16) * H_) + sl * 16;
#pragma unroll
                for (int i = 0; i < 16; ++i)
                    asm volatile("global_load_dwordx4 %0, %1, off sc0 sc1"
                                 : "=v"(tv[i]) : "v"(hsrc + i * 2048) : "memory");
            }
            // 2. pending logits store (w3; reads red parity p^1)
            if (w == 3 && doPend) {
                int r = lane >> 2, cq = (lane & 3) * 4;
                f32x4 o;
#pragma unroll
                for (int j = 0; j < 4; ++j)
                    o[j] = red[(p - 1) & 1][0][r][cq + j] + red[(p - 1) & 1][1][r][cq + j];
                int grow = qx * 128 + rg * 16 + r;
                *(f32x4*)&logits[((size_t)grow * L_ + (qs - 1)) * V_ + vcol0 + cq] = o;
            }
            // 3. logits MFMA: col ps-1 of half px, K half per wave
            if (doB) {
                const char* ha = (const char*)panel[px] + l15 * 2048;
                int kh = w - 2;
                f32x4 acc0 = {0.f,0.f,0.f,0.f}, acc1 = {0.f,0.f,0.f,0.f};
#pragma unroll
                for (int kk = 0; kk < 16; kk += 2) {
                    int k0 = kh * 512 + kk * 32 + l4 * 8;
                    int k1 = k0 + 32;
                    bf16x8 a0 = *(const bf16x8*)(ha + ((2 * k0) ^ as));
                    bf16x8 b0 = *(const bf16x8*)(wo + k0);
                    bf16x8 a1 = *(const bf16x8*)(ha + ((2 * k1) ^ as));
                    bf16x8 b1 = *(const bf16x8*)(wo + k1);
                    acc0 = __builtin_amdgcn_mfma_f32_16x16x32_bf16(a0, b0, acc0, 0, 0, 0);
                    acc1 = __builtin_amdgcn_mfma_f32_16x16x32_bf16(a1, b1, acc1, 0, 0, 0);
                }
#pragma unroll
                for (int j = 0; j < 4; ++j)
                    red[p & 1][kh][l4 * 4 + j][l15] = acc0[j] + acc1[j];
            }
            // 4. drain stage loads, swizzled panel write
            if (doStage) {
                asm volatile("s_waitcnt vmcnt(0)" ::: "memory");
                char* hd = (char*)panel[hx];
#pragma unroll
                for (int i = 0; i < 16; ++i) {
                    int b = sl * 16;
                    *(f32x4*)(hd + i * 2048 + (b ^ ((i & 7) << 4))) = tv[i];
                }
            }
        }
        __syncthreads();   // ONE barrier: panel[hx] ready, red/pend consumed, flags confirmed
    }
}

extern "C" void kernel_launch(void* const* d_in, const int* in_sizes, int n_in,
                              void* d_out, int out_size, void* d_ws, size_t ws_size,
                              hipStream_t stream)
{
    const int*   x   = (const int*)d_in[0];
    const float* hid = (const float*)d_in[1];
    const float* emb = (const float*)d_in[2];
    const float* We  = (const float*)d_in[3];
    const float* Wh  = (const float*)d_in[4];
    const float* Wo  = (const float*)d_in[5];

    float* logits  = (float*)d_out;                       // [B][L][V] f32
    float* final_h = logits + (size_t)B_ * L_ * V_;       // [B][H] f32

    char* ws = (char*)d_ws;
    float*  proj  = (float*)(ws);                                 // 1 MB   f32 [V][H]
    ushort* WhT   = (ushort*)(ws + (1u << 20));                   // 2 MB   bf16 [H][H]^T
    ushort* WoT   = (ushort*)(ws + 3u * (1u << 20));              // 0.5 MB bf16 [V][H]^T
    ushort* ringA = (ushort*)(ws + 3u * (1u << 20) + (1u << 19)); // 512 KB 2x[128][1024]
    ushort* ringB = (ushort*)(ws + 4u * (1u << 20));              // 512 KB 2x[128][1024]
    u8*     flags = (u8*)(ws + 4u * (1u << 20) + (1u << 19));     // 513 KB [2][8][513][64]

    const int FN = 2 * 8 * 513 * 64 / 4;   // flag words to zero
    k_zero<<<dim3((FN + 255) / 256), 256, 0, stream>>>((u32*)flags, FN);
    k_transpose_bf16<<<dim3(16, 16), 256, 0, stream>>>(Wh, WhT, H_, H_);
    k_transpose_bf16<<<dim3(4, 16),  256, 0, stream>>>(Wo, WoT, H_, V_);
    k_pack_h0<<<dim3(B_ * H_ / 256), 256, 0, stream>>>(hid, ringA, ringB);
    k_proj<<<dim3(256, 4), 256, 0, stream>>>(emb, We, proj);

    // one persistent kernel: 2x512 pipelined phases + drain
    k_scan<<<dim3(256), 256, 0, stream>>>(x, proj, WhT, WoT, ringA, ringB,
                                          logits, final_h, flags);
}

// Round 11
// 3118.508 us; speedup vs baseline: 1.5339x; 1.5339x over previous
//
#include <hip/hip_runtime.h>
#include <hip/hip_bf16.h>
#include <math.h>

#define B_ 256
#define L_ 512
#define V_ 256
#define E_ 256
#define H_ 1024

typedef float  f32x4  __attribute__((ext_vector_type(4)));
typedef short  bf16x8 __attribute__((ext_vector_type(8)));
typedef unsigned int u32;
typedef unsigned char u8;

static __device__ __forceinline__ ushort f2bf(float v) {
    __hip_bfloat16 b = __float2bfloat16(v);
    return *reinterpret_cast<ushort*>(&b);
}

// fast tanh: 1 - 2/(exp(2z)+1); exact limits, ~1e-7 rel err
static __device__ __forceinline__ float ftanh(float z) {
    float e = __expf(2.f * z);
    return 1.f - 2.f / (e + 1.f);
}

// ---------- prep: transpose f32 [R][C] -> bf16 [C][R] ----------
__global__ void k_transpose_bf16(const float* __restrict__ in, ushort* __restrict__ out,
                                 int R, int C) {
    __shared__ float tile[64][65];
    int bx = blockIdx.x, by = blockIdx.y;
    int tid = threadIdx.x;
    int g = tid >> 6, l = tid & 63;
    for (int i = 0; i < 16; ++i) {
        int r = g * 16 + i;
        tile[r][l] = in[(size_t)(by * 64 + r) * C + bx * 64 + l];
    }
    __syncthreads();
    for (int i = 0; i < 16; ++i) {
        int c = g * 16 + i;
        out[(size_t)(bx * 64 + c) * R + by * 64 + l] = f2bf(tile[l][c]);
    }
}

__global__ void k_f32_to_bf16(const float* __restrict__ in, ushort* __restrict__ out, int n) {
    int i = blockIdx.x * blockDim.x + threadIdx.x;
    if (i < n) out[i] = f2bf(in[i]);
}

__global__ void k_zero(u32* __restrict__ p, int n) {
    int i = blockIdx.x * blockDim.x + threadIdx.x;
    if (i < n) p[i] = 0u;
}

__global__ void k_proj(const float* __restrict__ emb, const float* __restrict__ We,
                       float* __restrict__ proj) {
    __shared__ float er[E_];
    int t = blockIdx.x;
    int h = blockIdx.y * 256 + threadIdx.x;
    er[threadIdx.x] = emb[t * E_ + threadIdx.x];
    __syncthreads();
    float acc = 0.f;
#pragma unroll 8
    for (int e = 0; e < E_; ++e) acc += er[e] * We[(size_t)e * H_ + h];
    proj[(size_t)t * H_ + h] = acc;
}

// ---------- chunked scan kernel (A-recurrence only) ----------
// 256 blocks, 1/CU. Block (rg=bid&7, cg=bid>>3): h rows [rg*32,+32) x cols
// [cg*32,+32) (R3-proven layout). Ring slot(H_t) = t % S; within a chunk of
// Tc <= S-1 steps NO slot is reused -> only sync is the group flag poll.
// Staging reads are sc0-only (L2-cached; fresh addresses within a chunk, so no
// staleness; group peers dedupe in their XCD L2). Producer data stores sc0 sc1
// (write-through to L3, no dirty L2 state); flags sc0 sc1 (bypass both ways).
// Cross-chunk / cross-kernel coherence comes from dispatch boundaries
// (empirically proven by R1's passing plain-load ping-pong).
__global__ __launch_bounds__(256, 1) void k_scan(
    const int* __restrict__ xs, const float* __restrict__ proj,
    const ushort* __restrict__ WhT, ushort* __restrict__ ring,
    float* __restrict__ final_h, u8* __restrict__ flags,
    int t0, int Tc, int S)
{
    __shared__ ushort lds_w[32 * 1024];   // W_h^T cols slice, swizzled (64KB)
    __shared__ ushort panel[32 * 1024];   // H_t rows slice, swizzled (64KB)
    __shared__ ushort stile[32 * 40];     // store repack, stride-40 (2.5KB)

    int tid = threadIdx.x;
    int w = tid >> 6, lane = tid & 63;
    int l15 = lane & 15, l4 = lane >> 4;
    int bid = blockIdx.x;
    int rg = bid & 7, cg = bid >> 3;
    int r0 = rg * 32, c0 = cg * 32;

    // W preload (plain; drained by first stage's vmcnt(0))
    {
        const char* wsrc = (const char*)(WhT + (size_t)c0 * H_);
        char* wd = (char*)lds_w;
        for (int i = 0; i < 16; ++i) {
            int chunk = (w * 16 + i) * 1024;
            int o = chunk + lane * 16;
            int row = o >> 11, b = o & 2047;
            int so = row * 2048 + (b ^ ((row & 7) << 4));
            __builtin_amdgcn_global_load_lds(
                (const __attribute__((address_space(1))) void*)(wsrc + so),
                (__attribute__((address_space(3))) void*)(wd + chunk), 16, 0, 0);
        }
    }

    int a = w >> 1, bc = w & 1;
    int arow = a * 16 + l15, brow = bc * 16 + l15;
    const char* ha = (const char*)panel + arow * 2048;
    const char* wa = (const char*)lds_w + brow * 2048;
    int as_ = (arow & 7) << 4, bs = (brow & 7) << 4;
    int gcol = c0 + bc * 16 + l15;

    for (int s = 0; s < Tc; ++s) {
        int t = t0 + s;
        // poll 32 per-producer flags for H_t (skip s=0: kernel boundary)
        if (s > 0 && w == 0) {
            const u8* fp = flags + (size_t)t * 256 + rg * 32 + lane;
            u32 v = 1u;
            while (true) {
                if (lane < 32)
                    asm volatile("global_load_ubyte %0, %1, off sc0 sc1\n\t"
                                 "s_waitcnt vmcnt(0)" : "=v"(v) : "v"(fp) : "memory");
                if (__ballot(v != 0u) == ~0ull) break;
            }
        }
        __syncthreads();

        // stage slot t%S: sc0-only loads (L2-cached, dedup), swizzled ds_write
        {
            const char* hsrc = (const char*)(ring + (size_t)(t % S) * B_ * H_
                                             + (size_t)r0 * H_) + tid * 16;
            f32x4 tv[16];
#pragma unroll
            for (int i = 0; i < 16; ++i)
                asm volatile("global_load_dwordx4 %0, %1, off sc0"
                             : "=v"(tv[i]) : "v"(hsrc + i * 4096) : "memory");
            asm volatile("s_waitcnt vmcnt(0)" ::: "memory");
            __builtin_amdgcn_sched_barrier(0);
#pragma unroll
            for (int i = 0; i < 16; ++i) {
                int o = i * 4096 + tid * 16;
                int row = o >> 11, b = o & 2047;
                *(f32x4*)((char*)panel + row * 2048 + (b ^ ((row & 7) << 4))) = tv[i];
            }
        }
        __syncthreads();

        // A: H_{t+1} tile = tanh(pv + H_t @ W_h)
        float pv[4];
#pragma unroll
        for (int j = 0; j < 4; ++j) {
            int grow = r0 + a * 16 + l4 * 4 + j;
            pv[j] = proj[(size_t)xs[grow * L_ + t] * H_ + gcol];
        }
        f32x4 acc0 = {0.f,0.f,0.f,0.f}, acc1 = {0.f,0.f,0.f,0.f};
#pragma unroll
        for (int kk = 0; kk < 32; kk += 2) {
            int kb0 = (kk * 32 + l4 * 8) * 2;
            int kb1 = ((kk + 1) * 32 + l4 * 8) * 2;
            bf16x8 af0 = *(const bf16x8*)(ha + (kb0 ^ as_));
            bf16x8 bf0 = *(const bf16x8*)(wa + (kb0 ^ bs));
            bf16x8 af1 = *(const bf16x8*)(ha + (kb1 ^ as_));
            bf16x8 bf1 = *(const bf16x8*)(wa + (kb1 ^ bs));
            acc0 = __builtin_amdgcn_mfma_f32_16x16x32_bf16(af0, bf0, acc0, 0, 0, 0);
            acc1 = __builtin_amdgcn_mfma_f32_16x16x32_bf16(af1, bf1, acc1, 0, 0, 0);
        }
#pragma unroll
        for (int j = 0; j < 4; ++j) {
            int lrow = a * 16 + l4 * 4 + j;
            float hv = ftanh((acc0[j] + acc1[j]) + pv[j]);
            stile[lrow * 40 + bc * 16 + l15] = f2bf(hv);
            if (t == L_ - 1) final_h[(size_t)(r0 + lrow) * H_ + gcol] = hv;
        }
        __syncthreads();

        // store 32x32 tile (2KB) write-through to slot (t+1)%S, drain, flag
        if (tid < 128) {
            int row = tid >> 2, seg = tid & 3;
            f32x4 d = *(const f32x4*)&stile[row * 40 + seg * 8];
            char* dst = (char*)(ring + (size_t)((t + 1) % S) * B_ * H_
                                + (size_t)(r0 + row) * H_ + c0 + seg * 8);
            asm volatile("global_store_dwordx4 %0, %1, off sc0 sc1"
                         :: "v"(dst), "v"(d) : "memory");
        }
        asm volatile("s_waitcnt vmcnt(0)" ::: "memory");
        __syncthreads();
        if (tid == 0) {
            u8* fdst = flags + (size_t)(t + 1) * 256 + rg * 32 + cg;
            u32 one = 1u;
            asm volatile("global_store_byte %0, %1, off sc0 sc1"
                         :: "v"(fdst), "v"(one) : "memory");
        }
    }
}

// ---------- per-chunk logits GEMM ----------
// grid 4*Tc: block (tl=bid>>2, q=bid&3) computes logits[:, t0+tl, :] rows
// [q*64,+64). A = ring slot (t+1)%S rows [q*64,+64) staged to 128KB LDS via
// global_load_lds (plain: kernel-boundary coherent). A-frags hoisted to 128
// VGPRs; B (WoT, L2-resident) streamed; kk-outer/vs-inner for 16-way MFMA ILP.
__global__ __launch_bounds__(256, 1) void k_logits(
    const ushort* __restrict__ ring, const ushort* __restrict__ WoT,
    float* __restrict__ logits, int t0, int S)
{
    __shared__ ushort Ap[64 * 1024];   // 128KB, swizzled
    int tid = threadIdx.x;
    int w = tid >> 6, lane = tid & 63;
    int l15 = lane & 15, l4 = lane >> 4;
    int bid = blockIdx.x;
    int tl = bid >> 2, q = bid & 3;
    int t = t0 + tl, slot = (t + 1) % S;

    {
        const char* asrc = (const char*)(ring + (size_t)slot * B_ * H_
                                         + (size_t)(q * 64) * H_);
        char* ad = (char*)Ap;
        for (int i = 0; i < 32; ++i) {
            int chunk = (w * 32 + i) * 1024;
            int o = chunk + lane * 16;
            int row = o >> 11, b = o & 2047;
            int so = row * 2048 + (b ^ ((row & 7) << 4));
            __builtin_amdgcn_global_load_lds(
                (const __attribute__((address_space(1))) void*)(asrc + so),
                (__attribute__((address_space(3))) void*)(ad + chunk), 16, 0, 0);
        }
    }
    asm volatile("s_waitcnt vmcnt(0)" ::: "memory");
    __syncthreads();

    int arow = w * 16 + l15;
    const char* ha = (const char*)Ap + (size_t)arow * 2048;
    int as_ = (arow & 7) << 4;
    bf16x8 af[32];
#pragma unroll
    for (int kk = 0; kk < 32; ++kk) {
        int kb = (kk * 32 + l4 * 8) * 2;
        af[kk] = *(const bf16x8*)(ha + (kb ^ as_));
    }
    f32x4 acc[16];
#pragma unroll
    for (int vs = 0; vs < 16; ++vs) acc[vs] = (f32x4){0.f, 0.f, 0.f, 0.f};
    const ushort* wob = WoT + (size_t)l15 * H_ + l4 * 8;
#pragma unroll
    for (int kk = 0; kk < 32; ++kk) {
#pragma unroll
        for (int vs = 0; vs < 16; ++vs) {
            bf16x8 bfr = *(const bf16x8*)(wob + (size_t)(vs * 16) * H_ + kk * 32);
            acc[vs] = __builtin_amdgcn_mfma_f32_16x16x32_bf16(af[kk], bfr, acc[vs], 0, 0, 0);
        }
    }
#pragma unroll
    for (int vs = 0; vs < 16; ++vs)
#pragma unroll
        for (int j = 0; j < 4; ++j) {
            int brow = q * 64 + w * 16 + l4 * 4 + j;
            logits[(size_t)brow * (L_ * V_) + (size_t)t * V_ + vs * 16 + l15] = acc[vs][j];
        }
}

extern "C" void kernel_launch(void* const* d_in, const int* in_sizes, int n_in,
                              void* d_out, int out_size, void* d_ws, size_t ws_size,
                              hipStream_t stream)
{
    const int*   x   = (const int*)d_in[0];
    const float* hid = (const float*)d_in[1];
    const float* emb = (const float*)d_in[2];
    const float* We  = (const float*)d_in[3];
    const float* Wh  = (const float*)d_in[4];
    const float* Wo  = (const float*)d_in[5];

    float* logits  = (float*)d_out;                       // [B][L][V] f32
    float* final_h = logits + (size_t)B_ * L_ * V_;       // [B][H] f32

    char* ws = (char*)d_ws;
    float*  proj  = (float*)(ws);                                  // 1 MB   @0
    ushort* WhT   = (ushort*)(ws + (1u << 20));                    // 2 MB   @1MB
    ushort* WoT   = (ushort*)(ws + 3u * (1u << 20));               // 0.5 MB @3MB
    u8*     flags = (u8*)(ws + 3u * (1u << 20) + (1u << 19));      // 131 KB @3.5MB
    const size_t RING_OFF = 3u * (1u << 20) + (1u << 19) + (1u << 18);  // 3.75MB
    ushort* ring  = (ushort*)(ws + RING_OFF);
    const size_t SLOT = (size_t)B_ * H_ * 2u;                      // 512 KB

    int S = (int)(ws_size > RING_OFF ? (ws_size - RING_OFF) / SLOT : 0);
    if (S > 65) S = 65;
    if (S < 2)  S = 2;

    // prep
    k_zero<<<dim3(129), 256, 0, stream>>>((u32*)flags, 513 * 256 / 4);
    k_transpose_bf16<<<dim3(16, 16), 256, 0, stream>>>(Wh, WhT, H_, H_);
    k_transpose_bf16<<<dim3(4, 16),  256, 0, stream>>>(Wo, WoT, H_, V_);
    k_f32_to_bf16<<<dim3(1024), 256, 0, stream>>>(hid, ring, B_ * H_);   // H_0 -> slot 0
    k_proj<<<dim3(256, 4), 256, 0, stream>>>(emb, We, proj);

    // chunked scan + per-chunk logits GEMM
    int T = S - 1;
    for (int t0 = 0; t0 < L_; t0 += T) {
        int Tc = (L_ - t0 < T) ? (L_ - t0) : T;
        k_scan<<<dim3(256), 256, 0, stream>>>(x, proj, WhT, ring,
                                              final_h, flags, t0, Tc, S);
        k_logits<<<dim3(4 * Tc), 256, 0, stream>>>(ring, WoT, logits, t0, S);
    }
}